// Round 3
// baseline (310.142 us; speedup 1.0000x reference)
//
#include <hip/hip_runtime.h>
#include <hip/hip_bf16.h>

typedef float f4 __attribute__((ext_vector_type(4)));
typedef short s8 __attribute__((ext_vector_type(8)));
typedef short s4 __attribute__((ext_vector_type(4)));

__device__ __forceinline__ short f2bf(float f) {
  union { float f; unsigned u; } v; v.f = f;
  unsigned r = v.u + 0x7fffu + ((v.u >> 16) & 1u);
  return (short)(r >> 16);
}
__device__ __forceinline__ float bf2f(short u) {
  union { unsigned q; float f; } v; v.q = ((unsigned)(unsigned short)u) << 16;
  return v.f;
}
// async global->LDS, 16B/lane, LDS dest = wave-uniform base + lane*16
__device__ __forceinline__ void gl16(const short* g, short* l) {
  __builtin_amdgcn_global_load_lds(
      (const __attribute__((address_space(1))) unsigned*)g,
      (__attribute__((address_space(3))) unsigned*)l, 16, 0, 0);
}

// ---------------------------------------------------------------------------
// Generic batched MFMA GEMM, C[m][n] = sum_k A[m][k]*B[n][k] (B^T layout,
// contraction contiguous in both operands). Tile 128 x BN, BK=64, 4 waves.
// Strides/batch-offsets in ELEMENTS, runtime. gl16 staging, linear LDS.
// ---------------------------------------------------------------------------
template<int BN, bool OUTF32, bool SWZ>
__global__ __launch_bounds__(256)
void mm_k(const short* __restrict__ A_, long Asb, int lda,
          const short* __restrict__ B_, long Bsb, int ldb,
          void* __restrict__ O_, long Osb, int ldo,
          int nkt, int nbm, int nbn) {
  __shared__ __align__(16) short As[128 * 64];
  __shared__ __align__(16) short Bs[BN * 64];
  int f = blockIdx.x;
  if (SWZ) { const int cpx = gridDim.x >> 3; f = (f & 7) * cpx + (f >> 3); }
  const int m0 = (f % nbm) * 128;
  const int t2 = f / nbm;
  const int n0 = (t2 % nbn) * BN;
  const int bz = t2 / nbn;
  const short* Ag = A_ + (long)bz * Asb;
  const short* Bg = B_ + (long)bz * Bsb;

  const int tid = threadIdx.x, lane = tid & 63, wid = tid >> 6;
  const int l15 = lane & 15, lhi = lane >> 4;
  const int wm = (wid >> 1) * 64, wn = (wid & 1) * (BN / 2);
  const int srow = tid >> 3, skc = (tid & 7) * 8;
  constexpr int NI = BN / 32;

  f4 acc[4][NI];
#pragma unroll
  for (int i = 0; i < 4; ++i)
#pragma unroll
    for (int j = 0; j < NI; ++j) acc[i][j] = (f4){0.f, 0.f, 0.f, 0.f};

  for (int kt = 0; kt < nkt; ++kt) {
    const int k0 = kt * 64;
    __syncthreads();
#pragma unroll
    for (int it = 0; it < 4; ++it) {
      const int r = it * 32 + srow;
      gl16(Ag + (long)(m0 + r) * lda + k0 + skc, &As[(it * 256 + tid) * 8]);
    }
#pragma unroll
    for (int it = 0; it < BN / 32; ++it) {
      const int r = it * 32 + srow;
      gl16(Bg + (long)(n0 + r) * ldb + k0 + skc, &Bs[(it * 256 + tid) * 8]);
    }
    __syncthreads();
#pragma unroll
    for (int kk = 0; kk < 64; kk += 32) {
      s8 af[4], bf[NI];
#pragma unroll
      for (int i = 0; i < 4; ++i)
        af[i] = *(const s8*)(&As[(wm + i * 16 + l15) * 64 + kk + lhi * 8]);
#pragma unroll
      for (int i = 0; i < NI; ++i)
        bf[i] = *(const s8*)(&Bs[(wn + i * 16 + l15) * 64 + kk + lhi * 8]);
#pragma unroll
      for (int mi = 0; mi < 4; ++mi)
#pragma unroll
        for (int ni = 0; ni < NI; ++ni)
          acc[mi][ni] = __builtin_amdgcn_mfma_f32_16x16x32_bf16(
              af[mi], bf[ni], acc[mi][ni], 0, 0, 0);
    }
  }

  // C/D layout: col = lane&15, row = (lane>>4)*4 + r
#pragma unroll
  for (int mi = 0; mi < 4; ++mi)
#pragma unroll
    for (int r = 0; r < 4; ++r) {
      const int grow = m0 + wm + mi * 16 + lhi * 4 + r;
#pragma unroll
      for (int ni = 0; ni < NI; ++ni) {
        const int col = n0 + wn + ni * 16 + l15;
        const float v = acc[mi][ni][r];
        if (OUTF32)
          ((float*)O_)[(long)bz * Osb + (long)grow * ldo + col] = v;
        else
          ((short*)O_)[(long)bz * Osb + (long)grow * ldo + col] = f2bf(v);
      }
    }
}

// ---------------------------------------------------------------------------
// Gram kernel: G = Z Z^T per batch (Z = [xc(384); qc(192); pad] bf16,
// K = 4096 split 4-way). Only the 19 needed 128x128 blocks. Writes f32
// partials Gpart[kc][b][640][640] (non-atomic, deterministic).
// ---------------------------------------------------------------------------
__global__ __launch_bounds__(256)
void gram_k(const short* __restrict__ Z, float* __restrict__ Gpart) {
  __shared__ __align__(16) short As[128 * 64];
  __shared__ __align__(16) short Bs[128 * 64];
  const int f = blockIdx.x;
  const int w = (f & 7) * 152 + (f >> 3);       // XCD chunk swizzle (1216/8)
  const int pair = w % 19;
  const int t2 = w / 19;
  const int kc = t2 & 3, bz = t2 >> 2;
  int bi, bj;
  if (pair < 9)      { bi = pair / 3;        bj = pair % 3; }
  else if (pair < 15){ int p = pair - 9;  bi = p / 2;     bj = 3 + (p & 1); }
  else               { int p = pair - 15; bi = 3 + p / 2; bj = 3 + (p & 1); }
  const int m0 = bi * 128, n0 = bj * 128;
  const short* Ag = Z + (long)bz * 640 * 4096 + (long)m0 * 4096 + kc * 1024;
  const short* Bg = Z + (long)bz * 640 * 4096 + (long)n0 * 4096 + kc * 1024;

  const int tid = threadIdx.x, lane = tid & 63, wid = tid >> 6;
  const int l15 = lane & 15, lhi = lane >> 4;
  const int wm = (wid >> 1) * 64, wn = (wid & 1) * 64;
  const int srow = tid >> 3, skc = (tid & 7) * 8;

  f4 acc[4][4];
#pragma unroll
  for (int i = 0; i < 4; ++i)
#pragma unroll
    for (int j = 0; j < 4; ++j) acc[i][j] = (f4){0.f, 0.f, 0.f, 0.f};

  for (int kt = 0; kt < 16; ++kt) {
    const int k0 = kt * 64;
    __syncthreads();
#pragma unroll
    for (int it = 0; it < 4; ++it) {
      const int r = it * 32 + srow;
      gl16(Ag + (long)r * 4096 + k0 + skc, &As[(it * 256 + tid) * 8]);
      gl16(Bg + (long)r * 4096 + k0 + skc, &Bs[(it * 256 + tid) * 8]);
    }
    __syncthreads();
#pragma unroll
    for (int kk = 0; kk < 64; kk += 32) {
      s8 af[4], bf[4];
#pragma unroll
      for (int i = 0; i < 4; ++i) {
        af[i] = *(const s8*)(&As[(wm + i * 16 + l15) * 64 + kk + lhi * 8]);
        bf[i] = *(const s8*)(&Bs[(wn + i * 16 + l15) * 64 + kk + lhi * 8]);
      }
#pragma unroll
      for (int mi = 0; mi < 4; ++mi)
#pragma unroll
        for (int ni = 0; ni < 4; ++ni)
          acc[mi][ni] = __builtin_amdgcn_mfma_f32_16x16x32_bf16(
              af[mi], bf[ni], acc[mi][ni], 0, 0, 0);
    }
  }
  float* Gp = Gpart + ((long)kc * 16 + bz) * 409600;
#pragma unroll
  for (int mi = 0; mi < 4; ++mi)
#pragma unroll
    for (int r = 0; r < 4; ++r) {
      const int grow = m0 + wm + mi * 16 + lhi * 4 + r;
#pragma unroll
      for (int ni = 0; ni < 4; ++ni)
        Gp[(long)grow * 640 + n0 + wn + ni * 16 + l15] = acc[mi][ni][r];
    }
}

// ---------------------------------------------------------------------------
// prep: x f32 -> Z rows 0..383 (cast) + xT (transpose+cast);
//       query f32 -> Z rows 384..575 (cast).
// ---------------------------------------------------------------------------
__global__ __launch_bounds__(256)
void prep_k(const float* __restrict__ x, const float* __restrict__ q,
            short* __restrict__ Z, short* __restrict__ xT) {
  const int role = blockIdx.x, b = blockIdx.z;
  const int s0 = blockIdx.y * 64;
  const int tid = threadIdx.x;
  const int rr = tid >> 4, cq = (tid & 15) * 4;
  short* Zb = Z + (long)b * 640 * 4096;
  if (role < 6) {
    __shared__ float Ls[64][65];
    const int c0 = role * 64;
    const float* xb = x + (long)b * 384 * 4096;
#pragma unroll
    for (int it = 0; it < 4; ++it) {
      const int r = it * 16 + rr;
      f4 v = *(const f4*)(xb + (long)(c0 + r) * 4096 + s0 + cq);
      s4 o; o[0] = f2bf(v.x); o[1] = f2bf(v.y); o[2] = f2bf(v.z); o[3] = f2bf(v.w);
      *(s4*)(&Zb[(long)(c0 + r) * 4096 + s0 + cq]) = o;
      Ls[r][cq + 0] = v.x; Ls[r][cq + 1] = v.y;
      Ls[r][cq + 2] = v.z; Ls[r][cq + 3] = v.w;
    }
    __syncthreads();
    short* xTb = xT + (long)b * 4096 * 384;
#pragma unroll
    for (int it = 0; it < 4; ++it) {
      const int sr = it * 16 + rr;
      s4 o;
#pragma unroll
      for (int j = 0; j < 4; ++j) o[j] = f2bf(Ls[cq + j][sr]);
      *(s4*)(&xTb[(long)(s0 + sr) * 384 + c0 + cq]) = o;
    }
  } else {
    const int c0 = (role - 6) * 64;
    const float* qb = q + (long)b * 192 * 4096;
#pragma unroll
    for (int it = 0; it < 4; ++it) {
      const int r = it * 16 + rr;
      f4 v = *(const f4*)(qb + (long)(c0 + r) * 4096 + s0 + cq);
      s4 o; o[0] = f2bf(v.x); o[1] = f2bf(v.y); o[2] = f2bf(v.z); o[3] = f2bf(v.w);
      *(s4*)(&Zb[(long)(384 + c0 + r) * 4096 + s0 + cq]) = o;
    }
  }
}

// reduce 4 K-partials -> Gbf bf16
__global__ void castg_k(const float* __restrict__ Gp, short* __restrict__ Gb) {
  const long i = ((long)blockIdx.x * 256 + threadIdx.x) * 4;
  const long slab = 640L * 640;
  const long b = i / slab, r = i % slab;
  f4 s = (f4){0.f, 0.f, 0.f, 0.f};
#pragma unroll
  for (int kc = 0; kc < 4; ++kc) {
    f4 v = *(const f4*)(Gp + ((long)kc * 16 + b) * slab + r);
    s.x += v.x; s.y += v.y; s.z += v.z; s.w += v.w;
  }
  s4 o; o[0] = f2bf(s.x); o[1] = f2bf(s.y); o[2] = f2bf(s.z); o[3] = f2bf(s.w);
  *(s4*)(&Gb[b * slab + r]) = o;
}

// ---------------------------------------------------------------------------
// softmax per (b,h): norms from W1/W2 row-dots, logits from Sraw, row
// softmax, write PT[d][c] = P[c][d] (full 384-wide rows incl. zeros).
// ---------------------------------------------------------------------------
__global__ __launch_bounds__(256)
void softmax_k(const float* __restrict__ Sraw, const short* __restrict__ W1,
               const short* __restrict__ W2, const short* __restrict__ wqb,
               const short* __restrict__ wkb, const float* __restrict__ temp,
               short* __restrict__ PT) {
  const int b = blockIdx.x, h = blockIdx.y, tid = threadIdx.x;
  __shared__ float nq[48], nk[48], L[2304], mrow[48], irow[48];
  if (tid < 48) {
    const int c = h * 48 + tid;
    const short* w1 = W1 + ((long)b * 384 + c) * 256;
    const short* wq = wqb + (long)c * 192;
    float s = 0.f;
    for (int a = 0; a < 192; ++a) s += bf2f(w1[a]) * bf2f(wq[a]);
    nq[tid] = fmaxf(s, 1e-12f);
  } else if (tid >= 64 && tid < 112) {
    const int d = h * 48 + (tid - 64);
    const short* w2 = W2 + ((long)b * 384 + d) * 384;
    const short* wk = wkb + (long)d * 384;
    float s = 0.f;
    for (int i = 0; i < 384; ++i) s += bf2f(w2[i]) * bf2f(wk[i]);
    nk[tid - 64] = fmaxf(s, 1e-12f);
  }
  __syncthreads();
  const float tp = temp[h];
  for (int i = tid; i < 2304; i += 256) {
    const int c = i / 48, d = i % 48;
    const float v = Sraw[((long)b * 384 + h * 48 + c) * 384 + h * 48 + d];
    L[i] = v * rsqrtf(nq[c]) * rsqrtf(nk[d]) * tp;
  }
  __syncthreads();
  if (tid < 48) {
    float m = -1e30f;
    for (int d = 0; d < 48; ++d) m = fmaxf(m, L[tid * 48 + d]);
    float s = 0.f;
    for (int d = 0; d < 48; ++d) s += __expf(L[tid * 48 + d] - m);
    mrow[tid] = m;
    irow[tid] = 1.f / s;
  }
  __syncthreads();
  for (int i = tid; i < 18432; i += 256) {
    const int d = i / 384, c = i % 384;
    const int ch = c - h * 48;
    float p = 0.f;
    if (ch >= 0 && ch < 48) p = __expf(L[ch * 48 + d] - mrow[ch]) * irow[ch];
    PT[((long)b * 384 + h * 48 + d) * 384 + c] = f2bf(p);
  }
}

// weights: wk (top of w_kv), wvT (transposed bottom), wq, wp -> bf16
__global__ void wprep_k(const float* __restrict__ wkv, const float* __restrict__ wq,
                        const float* __restrict__ wp, short* __restrict__ wkb,
                        short* __restrict__ wvT, short* __restrict__ wqb,
                        short* __restrict__ wpb) {
  const int i = blockIdx.x * 256 + threadIdx.x;
  if (i < 147456) {
    wkb[i] = f2bf(wkv[i]);
  } else if (i < 294912) {
    const int t = i - 147456;
    const int j = t / 384, d = t % 384;
    wvT[t] = f2bf(wkv[(384 + d) * 384 + j]);
  } else if (i < 368640) {
    wqb[i - 294912] = f2bf(wq[i - 294912]);
  } else if (i < 516096) {
    wpb[i - 368640] = f2bf(wp[i - 368640]);
  }
}

extern "C" void kernel_launch(void* const* d_in, const int* in_sizes, int n_in,
                              void* d_out, int out_size, void* d_ws, size_t ws_size,
                              hipStream_t stream) {
  const float* x = (const float*)d_in[0];
  const float* query = (const float*)d_in[1];
  const float* w_kv = (const float*)d_in[2];
  const float* w_q = (const float*)d_in[3];
  const float* w_proj = (const float*)d_in[4];
  const float* temp = (const float*)d_in[5];

  // workspace carve (~229 MiB of 384 MiB)
  char* w = (char*)d_ws;
  short* Z    = (short*)(w + 0);            // [16][640][4096] bf16 (84 MB)
  short* Gbf  = (short*)(w + 0);            // [16][640][640] bf16 — reuses Z
                                            // (written by castg AFTER gram)
  short* xT   = (short*)(w + 83886080);     // [16][4096][384] bf16 (50 MB)
  float* Gpart= (float*)(w + 134217728);    // [4][16][640][640] f32 (105 MB)
  // after castg consumes Gpart, its space hosts the small-chain buffers:
  short* W2b  = (short*)(w + 134217728);    // [16][384][384] bf16
  short* W1b  = (short*)(w + 138936320);    // [16][384][256] bf16
  short* Ucb  = (short*)(w + 142082048);    // [16][384][384] bf16
  float* Srawb= (float*)(w + 146800640);    // [16][384][384] f32
  short* PTb  = (short*)(w + 156237824);    // [16][384][384] bf16
  short* Yb   = (short*)(w + 160956416);    // [16][384][384] bf16
  short* Nbb  = (short*)(w + 165675008);    // [16][384][384] bf16
  short* wkb  = (short*)(w + 239075328);
  short* wvT  = (short*)(w + 239370240);
  short* wqb  = (short*)(w + 239665152);
  short* wpb  = (short*)(w + 239812608);
  float* out  = (float*)d_out;

  wprep_k<<<2016, 256, 0, stream>>>(w_kv, w_q, w_proj, wkb, wvT, wqb, wpb);
  // casts + transpose
  prep_k<<<dim3(9, 64, 16), 256, 0, stream>>>(x, query, Z, xT);
  // G = Z Z^T (19 needed blocks, K split 4)
  gram_k<<<1216, 256, 0, stream>>>(Z, Gpart);
  castg_k<<<6400, 256, 0, stream>>>(Gpart, Gbf);
  // W2[d][j] = sum_i wk[d,i] Gx[j,i]
  mm_k<128, false, false><<<144, 256, 0, stream>>>(
      wkb, 0, 384, Gbf, 409600, 640, W2b, 147456, 384, 6, 3, 3);
  // W1[c][a'] = sum_a wq[c,a] Gq[a',a]
  mm_k<128, false, false><<<96, 256, 0, stream>>>(
      wqb, 0, 192, Gbf + 384 * 640 + 384, 409600, 640, W1b, 98304, 256, 3, 3, 2);
  // Uc[c][i] = sum_a wq[c,a] Gxq[i,a]
  mm_k<128, false, false><<<144, 256, 0, stream>>>(
      wqb, 0, 192, Gbf + 384, 409600, 640, Ucb, 147456, 384, 3, 3, 3);
  // Sraw[c][d] = sum_i Uc[c,i] wk[d,i]   (f32 out)
  mm_k<128, true, false><<<144, 256, 0, stream>>>(
      Ucb, 147456, 384, wkb, 0, 384, Srawb, 147456, 384, 6, 3, 3);
  // norms + softmax -> PT
  softmax_k<<<dim3(16, 8), 256, 0, stream>>>(Srawb, W1b, W2b, wqb, wkb, temp, PTb);
  // Y[o][d] = sum_c wp[o,c] PT[d,c]
  mm_k<128, false, false><<<144, 256, 0, stream>>>(
      wpb, 0, 384, PTb, 147456, 384, Yb, 147456, 384, 6, 3, 3);
  // N[o][j] = sum_d Y[o,d] wvT[j,d]
  mm_k<128, false, false><<<144, 256, 0, stream>>>(
      Yb, 147456, 384, wvT, 0, 384, Nbb, 147456, 384, 6, 3, 3);
  // out[o][s] = sum_j N[o,j] xT[s,j]   (f32, BN=256, XCD swizzle)
  mm_k<256, true, true><<<768, 256, 0, stream>>>(
      Nbb, 147456, 384, xT, 1572864, 384, out, 1572864, 4096, 6, 3, 16);
}

// Round 4
// 237.219 us; speedup vs baseline: 1.3074x; 1.3074x over previous
//
#include <hip/hip_runtime.h>
#include <hip/hip_bf16.h>

typedef float f4 __attribute__((ext_vector_type(4)));
typedef short s8 __attribute__((ext_vector_type(8)));
typedef short s4 __attribute__((ext_vector_type(4)));

__device__ __forceinline__ short f2bf(float f) {
  union { float f; unsigned u; } v; v.f = f;
  unsigned r = v.u + 0x7fffu + ((v.u >> 16) & 1u);
  return (short)(r >> 16);
}
// async global->LDS, 16B/lane; LDS dest = wave-uniform base + lane*16 (linear)
__device__ __forceinline__ void gl16(const short* g, short* l) {
  __builtin_amdgcn_global_load_lds(
      (const __attribute__((address_space(1))) unsigned*)g,
      (__attribute__((address_space(3))) unsigned*)l, 16, 0, 0);
}

// ---------------------------------------------------------------------------
// MFMA GEMM, C[m][n] = sum_k A[m][k]*B[n][k] (contraction contiguous both
// sides). Tile 128x128, BK=64, 4 waves (2x2), 4x4 16x16x32 mfma.
// 2-phase double-buffered pipeline: stage(t+1) issued BEFORE compute(t),
// one __syncthreads (vmcnt0+barrier) per K-step.
// LDS bank-conflict fix (T2, rule #21): 16B-chunk XOR swizzle chunk^=(row&7)
// applied on the GLOBAL source address (gl16 dest stays linear) and on the
// ds_read side. 16-way conflict -> 2-way (free).
// ---------------------------------------------------------------------------
template<bool SUMSQ, bool OUTF32, bool SWZ>
__global__ __launch_bounds__(256)
void gemm3(const short* __restrict__ A_, long Asb, int lda,
           const short* __restrict__ B_, long Bsb, int ldb,
           void* __restrict__ O_, long Osb, int ldo,
           float* __restrict__ ss, int nkt, int nbm, int nbn) {
  __shared__ __align__(16) short As[2][8192];
  __shared__ __align__(16) short Bs[2][8192];
  int f = blockIdx.x;
  if (SWZ) { const int cpx = gridDim.x >> 3; f = (f & 7) * cpx + (f >> 3); }
  const int m0 = (f % nbm) * 128;
  const int t2 = f / nbm;
  const int n0 = (t2 % nbn) * 128;
  const int bz = t2 / nbn;
  const short* Ag = A_ + (long)bz * Asb;
  const short* Bg = B_ + (long)bz * Bsb;

  const int tid = threadIdx.x, lane = tid & 63, wid = tid >> 6;
  const int l15 = lane & 15, lhi = lane >> 4;
  const int wm = (wid >> 1) * 64, wn = (wid & 1) * 64;
  const int srow = tid >> 3;                       // staging row in 32-chunk
  const int skc = ((tid & 7) ^ (srow & 7)) * 8;    // XOR-swizzled src chunk

  f4 acc[4][4];
#pragma unroll
  for (int i = 0; i < 4; ++i)
#pragma unroll
    for (int j = 0; j < 4; ++j) acc[i][j] = (f4){0.f, 0.f, 0.f, 0.f};

  // prologue: stage K-step 0 into buffer 0
#pragma unroll
  for (int it = 0; it < 4; ++it) {
    const int r = it * 32 + srow;
    gl16(Ag + (long)(m0 + r) * lda + skc, &As[0][(it * 256 + tid) * 8]);
    gl16(Bg + (long)(n0 + r) * ldb + skc, &Bs[0][(it * 256 + tid) * 8]);
  }
  __syncthreads();

  for (int kt = 0; kt < nkt; ++kt) {
    const int cur = kt & 1;
    if (kt + 1 < nkt) {
      const int k1 = (kt + 1) * 64;
#pragma unroll
      for (int it = 0; it < 4; ++it) {
        const int r = it * 32 + srow;
        gl16(Ag + (long)(m0 + r) * lda + k1 + skc,
             &As[cur ^ 1][(it * 256 + tid) * 8]);
        gl16(Bg + (long)(n0 + r) * ldb + k1 + skc,
             &Bs[cur ^ 1][(it * 256 + tid) * 8]);
      }
    }
#pragma unroll
    for (int kk = 0; kk < 2; ++kk) {
      const int cb = ((lhi + kk * 4) ^ (l15 & 7)) * 8;  // swizzled read chunk
      s8 af[4], bf[4];
#pragma unroll
      for (int i = 0; i < 4; ++i) {
        af[i] = *(const s8*)(&As[cur][(wm + i * 16 + l15) * 64 + cb]);
        bf[i] = *(const s8*)(&Bs[cur][(wn + i * 16 + l15) * 64 + cb]);
      }
#pragma unroll
      for (int mi = 0; mi < 4; ++mi)
#pragma unroll
        for (int ni = 0; ni < 4; ++ni)
          acc[mi][ni] = __builtin_amdgcn_mfma_f32_16x16x32_bf16(
              af[mi], bf[ni], acc[mi][ni], 0, 0, 0);
    }
    __syncthreads();  // drains vmcnt (next tile landed) + joins waves
  }

  // epilogue: C/D layout col = lane&15, row = (lane>>4)*4 + r
#pragma unroll
  for (int mi = 0; mi < 4; ++mi)
#pragma unroll
    for (int r = 0; r < 4; ++r) {
      const int grow = m0 + wm + mi * 16 + lhi * 4 + r;
      if (SUMSQ) {
        float t = 0.f;
#pragma unroll
        for (int ni = 0; ni < 4; ++ni) { float v = acc[mi][ni][r]; t += v * v; }
        t += __shfl_xor(t, 1);
        t += __shfl_xor(t, 2);
        t += __shfl_xor(t, 4);
        t += __shfl_xor(t, 8);
        if (l15 == 0) atomicAdd(&ss[bz * 384 + grow], t);
      }
#pragma unroll
      for (int ni = 0; ni < 4; ++ni) {
        const int col = n0 + wn + ni * 16 + l15;
        const float v = acc[mi][ni][r];
        if (OUTF32)
          ((float*)O_)[(long)bz * Osb + (long)grow * ldo + col] = v;
        else
          ((short*)O_)[(long)bz * Osb + (long)grow * ldo + col] = f2bf(v);
      }
    }
}

// ---------------------------------------------------------------------------
// Transpose+cast: src f32 [16][C][4096] -> dst bf16 [16][4096][C].
// ---------------------------------------------------------------------------
__global__ __launch_bounds__(256)
void trans_k(const float* __restrict__ src, short* __restrict__ dst, int C) {
  __shared__ float Ls[64][65];
  const int tid = threadIdx.x;
  const int c0 = blockIdx.x * 64, s0 = blockIdx.y * 64;
  const long bb = (long)blockIdx.z * C * 4096;
  const int rr = tid >> 4;
  const int cq = (tid & 15) * 4;
#pragma unroll
  for (int it = 0; it < 4; ++it) {
    const int r = it * 16 + rr;
    f4 v = *(const f4*)(src + bb + (long)(c0 + r) * 4096 + s0 + cq);
    Ls[r][cq + 0] = v.x; Ls[r][cq + 1] = v.y;
    Ls[r][cq + 2] = v.z; Ls[r][cq + 3] = v.w;
  }
  __syncthreads();
  const long ob = (long)blockIdx.z * 4096 * C;
#pragma unroll
  for (int it = 0; it < 4; ++it) {
    const int sr = it * 16 + rr;
    s4 o;
#pragma unroll
    for (int j = 0; j < 4; ++j) o[j] = f2bf(Ls[cq + j][sr]);
    *(s4*)(&dst[ob + (long)(s0 + sr) * C + c0 + cq]) = o;
  }
}

// ---------------------------------------------------------------------------
// attn: partial raw-dot S[c][d] = sum_s Q[c,s]*K[d,s] per (b,h,zslice).
// Direct b128 global loads (each byte read once; spatial contiguous).
// ---------------------------------------------------------------------------
__global__ __launch_bounds__(256)
void attn_k(const short* __restrict__ Kb, const short* __restrict__ Qb,
            float* __restrict__ Spart) {
  const int b = blockIdx.x, h = blockIdx.y, z = blockIdx.z;
  const int tid = threadIdx.x;
  const int lane = tid & 63, wid = tid >> 6;
  const int l15 = lane & 15, lhi = lane >> 4;
  const long base = ((long)b * 384 + h * 48) * 4096;

  f4 acc[3][3];
#pragma unroll
  for (int i = 0; i < 3; ++i)
#pragma unroll
    for (int j = 0; j < 3; ++j) acc[i][j] = (f4){0.f, 0.f, 0.f, 0.f};

  const int sb = z * 1024 + wid * 256;
  for (int st = 0; st < 8; ++st) {
    const int s0 = sb + st * 32 + lhi * 8;
    s8 qa[3], ka[3];
#pragma unroll
    for (int i = 0; i < 3; ++i) {
      qa[i] = *(const s8*)(Qb + base + (long)(i * 16 + l15) * 4096 + s0);
      ka[i] = *(const s8*)(Kb + base + (long)(i * 16 + l15) * 4096 + s0);
    }
#pragma unroll
    for (int mi = 0; mi < 3; ++mi)
#pragma unroll
      for (int ni = 0; ni < 3; ++ni)
        acc[mi][ni] = __builtin_amdgcn_mfma_f32_16x16x32_bf16(
            qa[mi], ka[ni], acc[mi][ni], 0, 0, 0);
  }
  __shared__ float Sl[2304];
  for (int i = tid; i < 2304; i += 256) Sl[i] = 0.f;
  __syncthreads();
#pragma unroll
  for (int mi = 0; mi < 3; ++mi)
#pragma unroll
    for (int ni = 0; ni < 3; ++ni)
#pragma unroll
      for (int r = 0; r < 4; ++r) {
        int c = mi * 16 + lhi * 4 + r;
        int d = ni * 16 + l15;
        atomicAdd(&Sl[c * 48 + d], acc[mi][ni][r]);
      }
  __syncthreads();
  float* op = Spart + (((long)z * 16 + b) * 8 + h) * 2304;
  for (int i = tid; i < 2304; i += 256) op[i] = Sl[i];
}

// ---------------------------------------------------------------------------
// softmax per (b,h): reduce z-partials, logits = S*rnq*rnk*temp, row softmax,
// write PT[d][c] = P[c][d] as FULL 384-wide rows (zeros included -> no memset)
// ---------------------------------------------------------------------------
__global__ __launch_bounds__(256)
void softmax_k(const float* __restrict__ Spart, const float* __restrict__ ssq,
               const float* __restrict__ ssk, const float* __restrict__ temp,
               short* __restrict__ PT) {
  const int b = blockIdx.x, h = blockIdx.y, tid = threadIdx.x;
  __shared__ float L[2304];
  __shared__ float rq[48], rk[48], mrow[48], irow[48];
  if (tid < 48) {
    rq[tid] = 1.f / fmaxf(sqrtf(ssq[b * 384 + h * 48 + tid]), 1e-12f);
    rk[tid] = 1.f / fmaxf(sqrtf(ssk[b * 384 + h * 48 + tid]), 1e-12f);
  }
  __syncthreads();
  const float tp = temp[h];
  for (int i = tid; i < 2304; i += 256) {
    float v = 0.f;
#pragma unroll
    for (int z = 0; z < 4; ++z)
      v += Spart[(((long)z * 16 + b) * 8 + h) * 2304 + i];
    const int c = i / 48, d = i % 48;
    L[i] = v * rq[c] * rk[d] * tp;
  }
  __syncthreads();
  if (tid < 48) {
    float m = -1e30f;
    for (int d = 0; d < 48; ++d) m = fmaxf(m, L[tid * 48 + d]);
    float s = 0.f;
    for (int d = 0; d < 48; ++d) s += __expf(L[tid * 48 + d] - m);
    mrow[tid] = m;
    irow[tid] = 1.f / s;
  }
  __syncthreads();
  for (int i = tid; i < 18432; i += 256) {
    const int d = i / 384, c = i % 384;
    const int ch = c - h * 48;
    float p = 0.f;
    if (ch >= 0 && ch < 48) p = __expf(L[ch * 48 + d] - mrow[ch]) * irow[ch];
    PT[((long)b * 384 + h * 48 + d) * 384 + c] = f2bf(p);
  }
}

// weights -> bf16 (wk, wvT transposed, wq, wp) + zero ssq/ssk (no memsets)
__global__ void wprep_k(const float* __restrict__ wkv, const float* __restrict__ wq,
                        const float* __restrict__ wp, short* __restrict__ wkb,
                        short* __restrict__ wvT, short* __restrict__ wqb,
                        short* __restrict__ wpb, float* __restrict__ ssqk) {
  const int i = blockIdx.x * 256 + threadIdx.x;
  if (i < 12288) ssqk[i] = 0.f;
  if (i < 147456) {
    wkb[i] = f2bf(wkv[i]);
  } else if (i < 294912) {
    const int t = i - 147456;
    wvT[t] = f2bf(wkv[(384 + (t % 384)) * 384 + t / 384]);
  } else if (i < 368640) {
    wqb[i - 294912] = f2bf(wq[i - 294912]);
  } else {
    wpb[i - 368640] = f2bf(wp[i - 368640]);
  }
}

extern "C" void kernel_launch(void* const* d_in, const int* in_sizes, int n_in,
                              void* d_out, int out_size, void* d_ws, size_t ws_size,
                              hipStream_t stream) {
  const float* x = (const float*)d_in[0];
  const float* query = (const float*)d_in[1];
  const float* w_kv = (const float*)d_in[2];
  const float* w_q = (const float*)d_in[3];
  const float* w_proj = (const float*)d_in[4];
  const float* temp = (const float*)d_in[5];

  // workspace carve (~200 MB of 384 MiB), all offsets 16B-aligned
  char* w = (char*)d_ws;
  short* xT   = (short*)(w + 0);            // [16][4096][384] bf16
  short* qT   = (short*)(w + 50331648);     // [16][4096][192] bf16
  short* Kb   = (short*)(w + 75497472);     // [16][384][4096] bf16
  short* Qb   = (short*)(w + 125829120);    // [16][384][4096] bf16
  float* Spart= (float*)(w + 176160768);    // [4][16][8][2304] f32
  short* PTb  = (short*)(w + 195035136);    // [16][384][384] bf16
  short* Yb   = (short*)(w + 199753728);    // [16][384][384] bf16
  short* Nbb  = (short*)(w + 204472320);    // [16][384][384] bf16
  float* ssq  = (float*)(w + 209190912);    // [16][384] f32
  float* ssk  = (float*)(w + 209215488);    // [16][384] f32
  short* wkb  = (short*)(w + 209240064);
  short* wvT  = (short*)(w + 209534976);
  short* wqb  = (short*)(w + 209829888);
  short* wpb  = (short*)(w + 209977344);
  float* out  = (float*)d_out;

  // weights + zero the sumsq accumulators
  wprep_k<<<2016, 256, 0, stream>>>(w_kv, w_q, w_proj, wkb, wvT, wqb, wpb, ssq);
  // transposes + casts
  trans_k<<<dim3(6, 64, 16), 256, 0, stream>>>(x, xT, 384);
  trans_k<<<dim3(3, 64, 16), 256, 0, stream>>>(query, qT, 192);
  // Q = wq @ query^T-layout (+ssq)
  gemm3<true, false, true><<<1536, 256, 0, stream>>>(
      wqb, 0, 192, qT, 786432, 192, Qb, 1572864, 4096, ssq, 3, 3, 32);
  // K = wk @ x^T-layout (+ssk)
  gemm3<true, false, true><<<1536, 256, 0, stream>>>(
      wkb, 0, 384, xT, 1572864, 384, Kb, 1572864, 4096, ssk, 6, 3, 32);
  // raw channel dots, 4-way spatial split
  attn_k<<<dim3(16, 8, 4), 256, 0, stream>>>(Kb, Qb, Spart);
  // normalize + temperature + softmax -> PT (full rows)
  softmax_k<<<dim3(16, 8), 256, 0, stream>>>(Spart, ssq, ssk, temp, PTb);
  // Y[o][d] = sum_c wp[o,c] PT[d,c]
  gemm3<false, false, false><<<144, 256, 0, stream>>>(
      wpb, 0, 384, PTb, 147456, 384, Yb, 147456, 384, nullptr, 6, 3, 3);
  // N[o][j] = sum_d Y[o,d] wvT[j,d]
  gemm3<false, false, false><<<144, 256, 0, stream>>>(
      Yb, 147456, 384, wvT, 0, 384, Nbb, 147456, 384, nullptr, 6, 3, 3);
  // out[o][s] = sum_j N[o,j] xT[s,j]  (f32)
  gemm3<false, true, true><<<1536, 256, 0, stream>>>(
      Nbb, 147456, 384, xT, 1572864, 384, out, 1572864, 4096, nullptr, 6, 3, 32);
}

// Round 5
// 229.778 us; speedup vs baseline: 1.3497x; 1.0324x over previous
//
#include <hip/hip_runtime.h>
#include <hip/hip_bf16.h>

typedef float f4 __attribute__((ext_vector_type(4)));
typedef short s8 __attribute__((ext_vector_type(8)));
typedef short s4 __attribute__((ext_vector_type(4)));

__device__ __forceinline__ short f2bf(float f) {
  union { float f; unsigned u; } v; v.f = f;
  unsigned r = v.u + 0x7fffu + ((v.u >> 16) & 1u);
  return (short)(r >> 16);
}
// async global->LDS, 16B/lane; LDS dest = wave-uniform base + lane*16 (linear)
__device__ __forceinline__ void gl16(const short* g, short* l) {
  __builtin_amdgcn_global_load_lds(
      (const __attribute__((address_space(1))) unsigned*)g,
      (__attribute__((address_space(3))) unsigned*)l, 16, 0, 0);
}

// ---------------------------------------------------------------------------
// MFMA GEMM, C[m][n] = sum_k A[m][k]*B[n][k] (contraction contiguous both
// sides). Tile 128x128, BK=64, 4 waves (2x2), 4x4 16x16x32 mfma.
// 2-DEEP COUNTED-VMCNT pipeline (T4): prologue stages kt=0,1; per iter:
//   s_waitcnt vmcnt(8)   <- stage(kt) landed, stage(kt+1) stays IN FLIGHT
//   s_barrier; compute(kt); lgkmcnt(0); s_barrier; issue stage(kt+2)
// Loads get ~2 compute phases (~800cyc) to cover L2-cold HBM latency (~900).
// Final iter waits vmcnt(0) (NKT compile-time for exact counts).
// LDS XOR swizzle (T2, rule #21): chunk^=(row&7) pre-applied on the GLOBAL
// source address (gl16 dest linear) and on the ds_read side.
// ---------------------------------------------------------------------------
template<int NKT, bool SUMSQ, bool OUTF32, bool SWZ>
__global__ __launch_bounds__(256)
void gemm4(const short* __restrict__ A_, long Asb, int lda,
           const short* __restrict__ B_, long Bsb, int ldb,
           void* __restrict__ O_, long Osb, int ldo,
           float* __restrict__ ss, int nbm, int nbn) {
  __shared__ __align__(16) short As[2][8192];
  __shared__ __align__(16) short Bs[2][8192];
  int f = blockIdx.x;
  if (SWZ) { const int cpx = gridDim.x >> 3; f = (f & 7) * cpx + (f >> 3); }
  const int m0 = (f % nbm) * 128;
  const int t2 = f / nbm;
  const int n0 = (t2 % nbn) * 128;
  const int bz = t2 / nbn;
  const short* Ag = A_ + (long)bz * Asb;
  const short* Bg = B_ + (long)bz * Bsb;

  const int tid = threadIdx.x, lane = tid & 63, wid = tid >> 6;
  const int l15 = lane & 15, lhi = lane >> 4;
  const int wm = (wid >> 1) * 64, wn = (wid & 1) * 64;
  const int srow = tid >> 3;                       // staging row in 32-chunk
  const int skc = ((tid & 7) ^ (srow & 7)) * 8;    // XOR-swizzled src chunk

  f4 acc[4][4];
#pragma unroll
  for (int i = 0; i < 4; ++i)
#pragma unroll
    for (int j = 0; j < 4; ++j) acc[i][j] = (f4){0.f, 0.f, 0.f, 0.f};

  // prologue: stage kt=0 -> buf0, kt=1 -> buf1 (16 gl16 in flight/thread)
#pragma unroll
  for (int it = 0; it < 4; ++it) {
    const int r = it * 32 + srow;
    gl16(Ag + (long)(m0 + r) * lda + skc, &As[0][(it * 256 + tid) * 8]);
    gl16(Bg + (long)(n0 + r) * ldb + skc, &Bs[0][(it * 256 + tid) * 8]);
  }
  if (NKT > 1) {
#pragma unroll
    for (int it = 0; it < 4; ++it) {
      const int r = it * 32 + srow;
      gl16(Ag + (long)(m0 + r) * lda + 64 + skc, &As[1][(it * 256 + tid) * 8]);
      gl16(Bg + (long)(n0 + r) * ldb + 64 + skc, &Bs[1][(it * 256 + tid) * 8]);
    }
  }

#pragma unroll
  for (int kt = 0; kt < NKT; ++kt) {
    const int cur = kt & 1;
    // counted wait: stage(kt) landed; stage(kt+1)'s 8 loads stay in flight
    if (kt + 1 < NKT) asm volatile("s_waitcnt vmcnt(8)" ::: "memory");
    else              asm volatile("s_waitcnt vmcnt(0)" ::: "memory");
    __builtin_amdgcn_s_barrier();
    __builtin_amdgcn_sched_barrier(0);
#pragma unroll
    for (int kk = 0; kk < 2; ++kk) {
      const int cb = ((lhi + kk * 4) ^ (l15 & 7)) * 8;  // swizzled read chunk
      s8 af[4], bf[4];
#pragma unroll
      for (int i = 0; i < 4; ++i) {
        af[i] = *(const s8*)(&As[cur][(wm + i * 16 + l15) * 64 + cb]);
        bf[i] = *(const s8*)(&Bs[cur][(wn + i * 16 + l15) * 64 + cb]);
      }
#pragma unroll
      for (int mi = 0; mi < 4; ++mi)
#pragma unroll
        for (int ni = 0; ni < 4; ++ni)
          acc[mi][ni] = __builtin_amdgcn_mfma_f32_16x16x32_bf16(
              af[mi], bf[ni], acc[mi][ni], 0, 0, 0);
    }
    // all waves done reading buf[cur] (ds_reads drained) before refill
    asm volatile("s_waitcnt lgkmcnt(0)" ::: "memory");
    __builtin_amdgcn_s_barrier();
    if (kt + 2 < NKT) {
      const int k2 = (kt + 2) * 64;
#pragma unroll
      for (int it = 0; it < 4; ++it) {
        const int r = it * 32 + srow;
        gl16(Ag + (long)(m0 + r) * lda + k2 + skc,
             &As[cur][(it * 256 + tid) * 8]);
        gl16(Bg + (long)(n0 + r) * ldb + k2 + skc,
             &Bs[cur][(it * 256 + tid) * 8]);
      }
    }
  }

  // epilogue: C/D layout col = lane&15, row = (lane>>4)*4 + r
#pragma unroll
  for (int mi = 0; mi < 4; ++mi)
#pragma unroll
    for (int r = 0; r < 4; ++r) {
      const int grow = m0 + wm + mi * 16 + lhi * 4 + r;
      if (SUMSQ) {
        float t = 0.f;
#pragma unroll
        for (int ni = 0; ni < 4; ++ni) { float v = acc[mi][ni][r]; t += v * v; }
        t += __shfl_xor(t, 1);
        t += __shfl_xor(t, 2);
        t += __shfl_xor(t, 4);
        t += __shfl_xor(t, 8);
        if (l15 == 0) atomicAdd(&ss[bz * 384 + grow], t);
      }
#pragma unroll
      for (int ni = 0; ni < 4; ++ni) {
        const int col = n0 + wn + ni * 16 + l15;
        const float v = acc[mi][ni][r];
        if (OUTF32)
          ((float*)O_)[(long)bz * Osb + (long)grow * ldo + col] = v;
        else
          ((short*)O_)[(long)bz * Osb + (long)grow * ldo + col] = f2bf(v);
      }
    }
}

// ---------------------------------------------------------------------------
// Transpose+cast: src f32 [16][C][4096] -> dst bf16 [16][4096][C].
// ---------------------------------------------------------------------------
__global__ __launch_bounds__(256)
void trans_k(const float* __restrict__ src, short* __restrict__ dst, int C) {
  __shared__ float Ls[64][65];
  const int tid = threadIdx.x;
  const int c0 = blockIdx.x * 64, s0 = blockIdx.y * 64;
  const long bb = (long)blockIdx.z * C * 4096;
  const int rr = tid >> 4;
  const int cq = (tid & 15) * 4;
#pragma unroll
  for (int it = 0; it < 4; ++it) {
    const int r = it * 16 + rr;
    f4 v = *(const f4*)(src + bb + (long)(c0 + r) * 4096 + s0 + cq);
    Ls[r][cq + 0] = v.x; Ls[r][cq + 1] = v.y;
    Ls[r][cq + 2] = v.z; Ls[r][cq + 3] = v.w;
  }
  __syncthreads();
  const long ob = (long)blockIdx.z * 4096 * C;
#pragma unroll
  for (int it = 0; it < 4; ++it) {
    const int sr = it * 16 + rr;
    s4 o;
#pragma unroll
    for (int j = 0; j < 4; ++j) o[j] = f2bf(Ls[cq + j][sr]);
    *(s4*)(&dst[ob + (long)(s0 + sr) * C + c0 + cq]) = o;
  }
}

// ---------------------------------------------------------------------------
// attn: partial raw-dot S[c][d] = sum_s Q[c,s]*K[d,s] per (b,h,zslice).
// ---------------------------------------------------------------------------
__global__ __launch_bounds__(256)
void attn_k(const short* __restrict__ Kb, const short* __restrict__ Qb,
            float* __restrict__ Spart) {
  const int b = blockIdx.x, h = blockIdx.y, z = blockIdx.z;
  const int tid = threadIdx.x;
  const int lane = tid & 63, wid = tid >> 6;
  const int l15 = lane & 15, lhi = lane >> 4;
  const long base = ((long)b * 384 + h * 48) * 4096;

  f4 acc[3][3];
#pragma unroll
  for (int i = 0; i < 3; ++i)
#pragma unroll
    for (int j = 0; j < 3; ++j) acc[i][j] = (f4){0.f, 0.f, 0.f, 0.f};

  const int sb = z * 1024 + wid * 256;
  for (int st = 0; st < 8; ++st) {
    const int s0 = sb + st * 32 + lhi * 8;
    s8 qa[3], ka[3];
#pragma unroll
    for (int i = 0; i < 3; ++i) {
      qa[i] = *(const s8*)(Qb + base + (long)(i * 16 + l15) * 4096 + s0);
      ka[i] = *(const s8*)(Kb + base + (long)(i * 16 + l15) * 4096 + s0);
    }
#pragma unroll
    for (int mi = 0; mi < 3; ++mi)
#pragma unroll
      for (int ni = 0; ni < 3; ++ni)
        acc[mi][ni] = __builtin_amdgcn_mfma_f32_16x16x32_bf16(
            qa[mi], ka[ni], acc[mi][ni], 0, 0, 0);
  }
  __shared__ float Sl[2304];
  for (int i = tid; i < 2304; i += 256) Sl[i] = 0.f;
  __syncthreads();
#pragma unroll
  for (int mi = 0; mi < 3; ++mi)
#pragma unroll
    for (int ni = 0; ni < 3; ++ni)
#pragma unroll
      for (int r = 0; r < 4; ++r) {
        int c = mi * 16 + lhi * 4 + r;
        int d = ni * 16 + l15;
        atomicAdd(&Sl[c * 48 + d], acc[mi][ni][r]);
      }
  __syncthreads();
  float* op = Spart + (((long)z * 16 + b) * 8 + h) * 2304;
  for (int i = tid; i < 2304; i += 256) op[i] = Sl[i];
}

// ---------------------------------------------------------------------------
// softmax per (b,h): reduce z-partials, logits = S*rnq*rnk*temp, row softmax,
// write PT[d][c] = P[c][d] as FULL 384-wide rows (zeros included)
// ---------------------------------------------------------------------------
__global__ __launch_bounds__(256)
void softmax_k(const float* __restrict__ Spart, const float* __restrict__ ssq,
               const float* __restrict__ ssk, const float* __restrict__ temp,
               short* __restrict__ PT) {
  const int b = blockIdx.x, h = blockIdx.y, tid = threadIdx.x;
  __shared__ float L[2304];
  __shared__ float rq[48], rk[48], mrow[48], irow[48];
  if (tid < 48) {
    rq[tid] = 1.f / fmaxf(sqrtf(ssq[b * 384 + h * 48 + tid]), 1e-12f);
    rk[tid] = 1.f / fmaxf(sqrtf(ssk[b * 384 + h * 48 + tid]), 1e-12f);
  }
  __syncthreads();
  const float tp = temp[h];
  for (int i = tid; i < 2304; i += 256) {
    float v = 0.f;
#pragma unroll
    for (int z = 0; z < 4; ++z)
      v += Spart[(((long)z * 16 + b) * 8 + h) * 2304 + i];
    const int c = i / 48, d = i % 48;
    L[i] = v * rq[c] * rk[d] * tp;
  }
  __syncthreads();
  if (tid < 48) {
    float m = -1e30f;
    for (int d = 0; d < 48; ++d) m = fmaxf(m, L[tid * 48 + d]);
    float s = 0.f;
    for (int d = 0; d < 48; ++d) s += __expf(L[tid * 48 + d] - m);
    mrow[tid] = m;
    irow[tid] = 1.f / s;
  }
  __syncthreads();
  for (int i = tid; i < 18432; i += 256) {
    const int d = i / 384, c = i % 384;
    const int ch = c - h * 48;
    float p = 0.f;
    if (ch >= 0 && ch < 48) p = __expf(L[ch * 48 + d] - mrow[ch]) * irow[ch];
    PT[((long)b * 384 + h * 48 + d) * 384 + c] = f2bf(p);
  }
}

// weights -> bf16 (wk, wvT transposed, wq, wp) + zero ssq/ssk
__global__ void wprep_k(const float* __restrict__ wkv, const float* __restrict__ wq,
                        const float* __restrict__ wp, short* __restrict__ wkb,
                        short* __restrict__ wvT, short* __restrict__ wqb,
                        short* __restrict__ wpb, float* __restrict__ ssqk) {
  const int i = blockIdx.x * 256 + threadIdx.x;
  if (i < 12288) ssqk[i] = 0.f;
  if (i < 147456) {
    wkb[i] = f2bf(wkv[i]);
  } else if (i < 294912) {
    const int t = i - 147456;
    wvT[t] = f2bf(wkv[(384 + (t % 384)) * 384 + t / 384]);
  } else if (i < 368640) {
    wqb[i - 294912] = f2bf(wq[i - 294912]);
  } else {
    wpb[i - 368640] = f2bf(wp[i - 368640]);
  }
}

extern "C" void kernel_launch(void* const* d_in, const int* in_sizes, int n_in,
                              void* d_out, int out_size, void* d_ws, size_t ws_size,
                              hipStream_t stream) {
  const float* x = (const float*)d_in[0];
  const float* query = (const float*)d_in[1];
  const float* w_kv = (const float*)d_in[2];
  const float* w_q = (const float*)d_in[3];
  const float* w_proj = (const float*)d_in[4];
  const float* temp = (const float*)d_in[5];

  // workspace carve (~210 MB of 384 MiB), all offsets 16B-aligned
  char* w = (char*)d_ws;
  short* xT   = (short*)(w + 0);            // [16][4096][384] bf16
  short* qT   = (short*)(w + 50331648);     // [16][4096][192] bf16
  short* Kb   = (short*)(w + 75497472);     // [16][384][4096] bf16
  short* Qb   = (short*)(w + 125829120);    // [16][384][4096] bf16
  float* Spart= (float*)(w + 176160768);    // [4][16][8][2304] f32
  short* PTb  = (short*)(w + 195035136);    // [16][384][384] bf16
  short* Yb   = (short*)(w + 199753728);    // [16][384][384] bf16
  short* Nbb  = (short*)(w + 204472320);    // [16][384][384] bf16
  float* ssq  = (float*)(w + 209190912);    // [16][384] f32
  float* ssk  = (float*)(w + 209215488);    // [16][384] f32
  short* wkb  = (short*)(w + 209240064);
  short* wvT  = (short*)(w + 209534976);
  short* wqb  = (short*)(w + 209829888);
  short* wpb  = (short*)(w + 209977344);
  float* out  = (float*)d_out;

  // weights + zero the sumsq accumulators
  wprep_k<<<2016, 256, 0, stream>>>(w_kv, w_q, w_proj, wkb, wvT, wqb, wpb, ssq);
  // transposes + casts
  trans_k<<<dim3(6, 64, 16), 256, 0, stream>>>(x, xT, 384);
  trans_k<<<dim3(3, 64, 16), 256, 0, stream>>>(query, qT, 192);
  // Q = wq @ query^T-layout (+ssq)
  gemm4<3, true, false, true><<<1536, 256, 0, stream>>>(
      wqb, 0, 192, qT, 786432, 192, Qb, 1572864, 4096, ssq, 3, 32);
  // K = wk @ x^T-layout (+ssk)
  gemm4<6, true, false, true><<<1536, 256, 0, stream>>>(
      wkb, 0, 384, xT, 1572864, 384, Kb, 1572864, 4096, ssk, 3, 32);
  // raw channel dots, 4-way spatial split
  attn_k<<<dim3(16, 8, 4), 256, 0, stream>>>(Kb, Qb, Spart);
  // normalize + temperature + softmax -> PT (full rows)
  softmax_k<<<dim3(16, 8), 256, 0, stream>>>(Spart, ssq, ssk, temp, PTb);
  // Y[o][d] = sum_c wp[o,c] PT[d,c]
  gemm4<6, false, false, false><<<144, 256, 0, stream>>>(
      wpb, 0, 384, PTb, 147456, 384, Yb, 147456, 384, nullptr, 3, 3);
  // N[o][j] = sum_d Y[o,d] wvT[j,d]
  gemm4<6, false, false, false><<<144, 256, 0, stream>>>(
      Yb, 147456, 384, wvT, 0, 384, Nbb, 147456, 384, nullptr, 3, 3);
  // out[o][s] = sum_j N[o,j] xT[s,j]  (f32)
  gemm4<6, false, true, true><<<1536, 256, 0, stream>>>(
      Nbb, 147456, 384, xT, 1572864, 384, out, 1572864, 4096, nullptr, 3, 32);
}